// Round 2
// baseline (5980.909 us; speedup 1.0000x reference)
//
#include <hip/hip_runtime.h>
#include <hip/hip_bf16.h>

constexpr int Bb = 4, Nn = 2048, NH = 8;
constexpr int MROWS = Bb * Nn;          // 8192
constexpr int CHUNK = 128;              // q-rows per attention chunk
constexpr int NCHUNK = Nn / CHUNK;      // 16

constexpr int BK = 16, PAD = 68;

// ---------------- generic tiled GEMM: C = A @ W + bias -----------------
// AMODE: 0 = A fp32 dense [M,K]
//        1 = concat: fp32 A1 [M,K1] then fp32 A2 [M,K-K1]
// EPI:   0 = store fp32 C; 1 = store fp32 C with fp32 residual added
template<int AMODE, int EPI>
__global__ __launch_bounds__(256)
void gemm_k(const float* __restrict__ A1, const float* __restrict__ A2,
            const float* __restrict__ W, const float* __restrict__ bias,
            float* __restrict__ C, const float* __restrict__ resid,
            int M, int N, int K, int K1)
{
  __shared__ float As[BK][PAD];
  __shared__ float Ws[BK][PAD];
  const int tid = threadIdx.x;
  const int tx = tid & 15, ty = tid >> 4;
  const int row0 = blockIdx.x * 64, col0 = blockIdx.y * 64;
  float acc[4][4] = {};
  for (int kt = 0; kt < K; kt += BK) {
    for (int e = tid; e < 64 * BK; e += 256) {
      const int kk = e & 15, m = e >> 4;
      const int gk = kt + kk;
      const int gr = row0 + m;
      float v;
      if constexpr (AMODE == 0) v = A1[(size_t)gr * K + gk];
      else v = (gk < K1) ? A1[(size_t)gr * K1 + gk]
                         : A2[(size_t)gr * (K - K1) + (gk - K1)];
      As[kk][m] = v;
    }
    for (int e = tid; e < 64 * BK; e += 256) {
      const int n = e & 63, kk = e >> 6;
      Ws[kk][n] = W[(size_t)(kt + kk) * N + col0 + n];
    }
    __syncthreads();
#pragma unroll
    for (int kk = 0; kk < BK; ++kk) {
      const float4 a4 = *(const float4*)&As[kk][ty * 4];
      const float4 w4 = *(const float4*)&Ws[kk][tx * 4];
      const float a[4] = {a4.x, a4.y, a4.z, a4.w};
      const float w[4] = {w4.x, w4.y, w4.z, w4.w};
#pragma unroll
      for (int i = 0; i < 4; ++i)
#pragma unroll
        for (int j = 0; j < 4; ++j)
          acc[i][j] = fmaf(a[i], w[j], acc[i][j]);
    }
    __syncthreads();
  }
#pragma unroll
  for (int i = 0; i < 4; ++i) {
    const int r = row0 + ty * 4 + i;
#pragma unroll
    for (int j = 0; j < 4; ++j) {
      const int c = col0 + tx * 4 + j;
      float v = acc[i][j] + bias[c];
      if constexpr (EPI == 1) v += resid[(size_t)r * N + c];
      C[(size_t)r * N + c] = v;
    }
  }
}

// ---------------- RoPE in-place on interleaved qkv ---------------------
// qkv[b,n, h*192 + d*3 + s], s=0:q 1:k 2:v.
// out[2t]   = x[2t]*f0[2t]   - x[2t+1]*f1[2t]
// out[2t+1] = x[2t+1]*f0[2t+1] + x[2t]*f1[2t+1]
__global__ __launch_bounds__(256)
void rope_k(float* __restrict__ qkv, const float* __restrict__ enc)
{
  const long idx = (long)blockIdx.x * 256 + threadIdx.x; // [0, B*N*H*32)
  const int t = idx & 31;
  const int h = (int)((idx >> 5) & 7);
  const long bn = idx >> 8;                 // b*Nn + n
  const int d0 = 2 * t, d1 = 2 * t + 1;
  const long ebase = bn * 64;               // enc[s][b][0][n][d]
  const long e1 = (long)Bb * Nn * 64;
  const float f0a = enc[ebase + d0], f0b = enc[ebase + d1];
  const float f1a = enc[e1 + ebase + d0], f1b = enc[e1 + ebase + d1];
  const long base = bn * 1536 + (long)h * 192;
#pragma unroll
  for (int s = 0; s < 2; ++s) {
    const float x0 = qkv[base + d0 * 3 + s];
    const float x1 = qkv[base + d1 * 3 + s];
    qkv[base + d0 * 3 + s] = x0 * f0a - x1 * f1a;
    qkv[base + d1 * 3 + s] = x1 * f0b + x0 * f1b;
  }
}

// ---------------- attention scores: S = Qc @ K^T -----------------------
// grid (CHUNK/64, Nn/64, 32)
__global__ __launch_bounds__(256)
void gemm_scores(const float* __restrict__ qkv, float* __restrict__ S, int n0)
{
  __shared__ float As[BK][PAD];
  __shared__ float Bs[BK][PAD];
  const int tid = threadIdx.x;
  const int tx = tid & 15, ty = tid >> 4;
  const int bh = blockIdx.z;
  const int b = bh >> 3, h = bh & 7;
  const int row0 = blockIdx.x * 64, col0 = blockIdx.y * 64;
  float acc[4][4] = {};
  for (int kt = 0; kt < 64; kt += BK) {
    for (int e = tid; e < 64 * BK; e += 256) {
      const int kk = e & 15, m = e >> 4;
      const int d = kt + kk;
      As[kk][m] = qkv[((size_t)b * Nn + n0 + row0 + m) * 1536 + h * 192 + d * 3 + 0];
      Bs[kk][m] = qkv[((size_t)b * Nn + col0 + m) * 1536 + h * 192 + d * 3 + 1];
    }
    __syncthreads();
#pragma unroll
    for (int kk = 0; kk < BK; ++kk) {
      const float4 a4 = *(const float4*)&As[kk][ty * 4];
      const float4 w4 = *(const float4*)&Bs[kk][tx * 4];
      const float a[4] = {a4.x, a4.y, a4.z, a4.w};
      const float w[4] = {w4.x, w4.y, w4.z, w4.w};
#pragma unroll
      for (int i = 0; i < 4; ++i)
#pragma unroll
        for (int j = 0; j < 4; ++j)
          acc[i][j] = fmaf(a[i], w[j], acc[i][j]);
    }
    __syncthreads();
  }
#pragma unroll
  for (int i = 0; i < 4; ++i)
#pragma unroll
    for (int j = 0; j < 4; ++j)
      S[((size_t)bh * CHUNK + row0 + ty * 4 + i) * Nn + col0 + tx * 4 + j] = acc[i][j];
}

// ---------------- row softmax (in place), scale 1/8 --------------------
__global__ __launch_bounds__(256)
void softmax_rows(float* __restrict__ S)
{
  float* row = S + (size_t)blockIdx.x * Nn;
  __shared__ float red[256];
  const int tid = threadIdx.x;
  float vals[8];
  float mx = -1e30f;
#pragma unroll
  for (int i = 0; i < 8; ++i) {
    vals[i] = row[tid + 256 * i] * 0.125f;
    mx = fmaxf(mx, vals[i]);
  }
  red[tid] = mx; __syncthreads();
  for (int s = 128; s > 0; s >>= 1) {
    if (tid < s) red[tid] = fmaxf(red[tid], red[tid + s]);
    __syncthreads();
  }
  mx = red[0]; __syncthreads();
  float sm = 0.f;
#pragma unroll
  for (int i = 0; i < 8; ++i) { vals[i] = __expf(vals[i] - mx); sm += vals[i]; }
  red[tid] = sm; __syncthreads();
  for (int s = 128; s > 0; s >>= 1) {
    if (tid < s) red[tid] += red[tid + s];
    __syncthreads();
  }
  const float inv = 1.f / red[0];
#pragma unroll
  for (int i = 0; i < 8; ++i) row[tid + 256 * i] = vals[i] * inv;
}

// ---------------- PV: O += P @ V (split-K over keys, atomic) -----------
// grid (CHUNK/64, 1, 32*4)
__global__ __launch_bounds__(256)
void gemm_pv(const float* __restrict__ S, const float* __restrict__ qkv,
             float* __restrict__ O, int n0)
{
  __shared__ float As[BK][PAD];
  __shared__ float Bs[BK][PAD];
  const int tid = threadIdx.x;
  const int tx = tid & 15, ty = tid >> 4;
  const int zz = blockIdx.z;
  const int bh = zz >> 2, seg = zz & 3;
  const int b = bh >> 3, h = bh & 7;
  const int row0 = blockIdx.x * 64;
  float acc[4][4] = {};
  for (int kt = seg * 512; kt < seg * 512 + 512; kt += BK) {
    for (int e = tid; e < 64 * BK; e += 256) {
      const int kk = e & 15, m = e >> 4;
      As[kk][m] = S[((size_t)bh * CHUNK + row0 + m) * Nn + kt + kk];
    }
    for (int e = tid; e < 64 * BK; e += 256) {
      const int dn = e & 63, kk = e >> 6;
      Bs[kk][dn] = qkv[((size_t)b * Nn + kt + kk) * 1536 + h * 192 + dn * 3 + 2];
    }
    __syncthreads();
#pragma unroll
    for (int kk = 0; kk < BK; ++kk) {
      const float4 a4 = *(const float4*)&As[kk][ty * 4];
      const float4 w4 = *(const float4*)&Bs[kk][tx * 4];
      const float a[4] = {a4.x, a4.y, a4.z, a4.w};
      const float w[4] = {w4.x, w4.y, w4.z, w4.w};
#pragma unroll
      for (int i = 0; i < 4; ++i)
#pragma unroll
        for (int j = 0; j < 4; ++j)
          acc[i][j] = fmaf(a[i], w[j], acc[i][j]);
    }
    __syncthreads();
  }
#pragma unroll
  for (int i = 0; i < 4; ++i)
#pragma unroll
    for (int j = 0; j < 4; ++j)
      atomicAdd(&O[((size_t)b * Nn + n0 + row0 + ty * 4 + i) * 512 + h * 64 + tx * 4 + j],
                acc[i][j]);
}

// ---------------- LayerNorm + exact GELU -------------------------------
__global__ __launch_bounds__(256)
void ln_gelu_k(const float* __restrict__ H, const float* __restrict__ g,
               const float* __restrict__ be, float* __restrict__ G)
{
  const float* row = H + (size_t)blockIdx.x * 1024;
  const int tid = threadIdx.x;
  __shared__ float rs_[256], rq_[256];
  float v[4];
  float s = 0.f, sq = 0.f;
#pragma unroll
  for (int i = 0; i < 4; ++i) {
    v[i] = row[tid + 256 * i];
    s += v[i]; sq += v[i] * v[i];
  }
  rs_[tid] = s; rq_[tid] = sq; __syncthreads();
  for (int st = 128; st > 0; st >>= 1) {
    if (tid < st) { rs_[tid] += rs_[tid + st]; rq_[tid] += rq_[tid + st]; }
    __syncthreads();
  }
  const float mu = rs_[0] * (1.f / 1024.f);
  const float var = rq_[0] * (1.f / 1024.f) - mu * mu;
  const float rstd = rsqrtf(var + 1e-5f);
#pragma unroll
  for (int i = 0; i < 4; ++i) {
    const int c = tid + 256 * i;
    const float y = (v[i] - mu) * rstd * g[c] + be[c];
    G[(size_t)blockIdx.x * 1024 + c] = 0.5f * y * (1.f + erff(y * 0.70710678118f));
  }
}

extern "C" void kernel_launch(void* const* d_in, const int* in_sizes, int n_in,
                              void* d_out, int out_size, void* d_ws, size_t ws_size,
                              hipStream_t stream)
{
  const float* x[2]   = {(const float*)d_in[0], (const float*)d_in[1]};
  const float* enc[2] = {(const float*)d_in[2], (const float*)d_in[3]};
  const float* Wqkv  = (const float*)d_in[4];
  const float* bqkv  = (const float*)d_in[5];
  const float* Wproj = (const float*)d_in[6];
  const float* bproj = (const float*)d_in[7];
  const float* W1    = (const float*)d_in[8];
  const float* b1    = (const float*)d_in[9];
  const float* ln_g  = (const float*)d_in[10];
  const float* ln_b  = (const float*)d_in[11];
  const float* W2    = (const float*)d_in[12];
  const float* b2    = (const float*)d_in[13];

  float* ws = (float*)d_ws;
  float* qkvb = ws;                       // 12,582,912 floats (50.3 MB)
  float* Sbuf = ws + 12582912;            //  8,388,608 floats (33.5 MB)
  float* obuf = ws + 20971520;            //  4,194,304 floats (16.8 MB)
  float* msg  = Sbuf + 4194304;           // alias: upper half of S region
  float* hbuf = qkvb;                     // alias (qkv dead after attention)
  float* gbuf = Sbuf;                     // alias (S & msg dead by step 7)
  // total ws: 25,165,824 floats = 100.7 MB

  for (int blk = 0; blk < 2; ++blk) {
    // 1. qkv = x @ Wqkv + bqkv                      [8192,1536]
    gemm_k<0, 0><<<dim3(128, 24), 256, 0, stream>>>(
        x[blk], nullptr, Wqkv, bqkv, qkvb, nullptr, MROWS, 1536, 512, 0);
    // 2. RoPE in place on q,k
    rope_k<<<8192, 256, 0, stream>>>(qkvb, enc[blk]);
    // 3. zero attention output (split-K accumulates atomically)
    hipMemsetAsync(obuf, 0, (size_t)4194304 * 4, stream);
    // 4. attention, chunked over q-rows
    for (int c = 0; c < NCHUNK; ++c) {
      const int n0 = c * CHUNK;
      gemm_scores<<<dim3(CHUNK / 64, Nn / 64, 32), 256, 0, stream>>>(qkvb, Sbuf, n0);
      softmax_rows<<<32 * CHUNK, 256, 0, stream>>>(Sbuf);
      gemm_pv<<<dim3(CHUNK / 64, 1, 32 * 4), 256, 0, stream>>>(Sbuf, qkvb, obuf, n0);
    }
    // 5. message = o @ Wproj + bproj                [8192,512]
    gemm_k<0, 0><<<dim3(128, 8), 256, 0, stream>>>(
        obuf, nullptr, Wproj, bproj, msg, nullptr, MROWS, 512, 512, 0);
    // 6. h = [x | message] @ W1 + b1                [8192,1024]
    gemm_k<1, 0><<<dim3(128, 16), 256, 0, stream>>>(
        x[blk], msg, W1, b1, hbuf, nullptr, MROWS, 1024, 1024, 512);
    // 7. LayerNorm + GELU
    ln_gelu_k<<<8192, 256, 0, stream>>>(hbuf, ln_g, ln_b, gbuf);
    // 8. out = x + gelu_h @ W2 + b2                 [8192,512] fp32
    gemm_k<0, 1><<<dim3(128, 8), 256, 0, stream>>>(
        gbuf, nullptr, W2, b2,
        (float*)d_out + (size_t)blk * MROWS * 512, x[blk], MROWS, 512, 1024, 0);
  }
}

// Round 3
// 1128.092 us; speedup vs baseline: 5.3018x; 5.3018x over previous
//
#include <hip/hip_runtime.h>
#include <hip/hip_bf16.h>

typedef __attribute__((ext_vector_type(8))) short   short8v;
typedef __attribute__((ext_vector_type(8))) __bf16  bf16x8;
typedef __attribute__((ext_vector_type(4))) float   f32x4;

constexpr int Bb = 4, Nn = 2048;
constexpr int MROWS = 8192;
constexpr int CHUNK = 256, NCHUNK = Nn / CHUNK;   // 8 chunks

#define GLOAD_LDS(src, dst) \
  __builtin_amdgcn_global_load_lds((__attribute__((address_space(1))) unsigned int*)(src), \
                                   (__attribute__((address_space(3))) unsigned int*)(dst), 16, 0, 0)

// =====================================================================
// MFMA GEMM: C[M,N] = A[M,K] @ B[K,N] (+bias)(+resid), B passed as B^T [N][K].
// Tile 128 x (32*NFR), BK=32, 256 threads = 4 waves (2x2).
// AMODE 0: dense A. AMODE 1: concat (A cols [0,K1) | A2 cols [K1,K)), same lda.
// EPI 0: fp32 +bias | 1: bf16 +bias | 2: fp32 +bias+resid | 3: bf16 plain | 4: atomicAdd fp32
// blockIdx.z: bh = z>>log2split, seg = z&((1<<log2split)-1); K range = [seg*ksz, (seg+1)*ksz)
// =====================================================================
template<int NFR, int AMODE, int EPI>
__global__ __launch_bounds__(256)
void gemm_mfma(const __bf16* __restrict__ A, const __bf16* __restrict__ A2,
               const __bf16* __restrict__ BT,
               const float* __restrict__ bias, const float* __restrict__ resid,
               float* __restrict__ Cf, __bf16* __restrict__ Cb,
               int lda, int ldb, int ldc, int K1,
               int ksz, int log2split,
               long sAz, long sBz, long sCzb, long sCzh)
{
  constexpr int TN = 32 * NFR;          // 128 or 64
  constexpr int WN = TN / 2;            // per-wave N
  __shared__ __align__(16) __bf16 As[128 * 32];
  __shared__ __align__(16) __bf16 Bs[TN * 32];
  const int tid = threadIdx.x;
  const int w = tid >> 6, l = tid & 63;
  const int wr = w >> 1, wc = w & 1;
  const int lr = l & 15, lg = l >> 4;
  const int z = blockIdx.z;
  const int seg = z & ((1 << log2split) - 1);
  const int bh = z >> log2split;
  const int row0 = blockIdx.x * 128, col0 = blockIdx.y * TN;
  const int kbeg = seg * ksz, kend = kbeg + ksz;

  const __bf16* Abase = A + (size_t)bh * sAz;
  const __bf16* Bbase = BT + (size_t)bh * sBz;
  const long coff = (long)(bh >> 3) * sCzb + (long)(bh & 7) * sCzh;

  f32x4 acc[4][NFR];
#pragma unroll
  for (int i = 0; i < 4; ++i)
#pragma unroll
    for (int j = 0; j < NFR; ++j) acc[i][j] = (f32x4){0.f, 0.f, 0.f, 0.f};

  const int srow = l >> 2;            // staging: row within 16-row segment
  const int skk  = (l & 3) * 8;       // staging: k offset (8 bf16 = 16 B)

  for (int k0 = kbeg; k0 < kend; k0 += 32) {
    // stage A tile [128][32]
    for (int s = w; s < 8; s += 4) {
      const int m = s * 16 + srow;
      const __bf16* src;
      if constexpr (AMODE == 0) {
        src = Abase + (size_t)(row0 + m) * lda + k0 + skk;
      } else {
        const int gk = k0 + skk;
        src = (gk < K1) ? A  + (size_t)(row0 + m) * lda + gk
                        : A2 + (size_t)(row0 + m) * lda + (gk - K1);
      }
      GLOAD_LDS(src, &As[s * 512]);
    }
    // stage B^T tile [TN][32]
    for (int s = w; s < TN / 16; s += 4) {
      const int n = s * 16 + srow;
      const __bf16* src = Bbase + (size_t)(col0 + n) * ldb + k0 + skk;
      GLOAD_LDS(src, &Bs[s * 512]);
    }
    __syncthreads();
    bf16x8 af[4], bfv[NFR];
#pragma unroll
    for (int mi = 0; mi < 4; ++mi)
      af[mi] = *(const bf16x8*)&As[(wr * 64 + mi * 16 + lr) * 32 + lg * 8];
#pragma unroll
    for (int ni = 0; ni < NFR; ++ni)
      bfv[ni] = *(const bf16x8*)&Bs[(wc * WN + ni * 16 + lr) * 32 + lg * 8];
#pragma unroll
    for (int mi = 0; mi < 4; ++mi)
#pragma unroll
      for (int ni = 0; ni < NFR; ++ni)
        acc[mi][ni] = __builtin_amdgcn_mfma_f32_16x16x32_bf16(af[mi], bfv[ni], acc[mi][ni], 0, 0, 0);
    __syncthreads();
  }
  // epilogue: lane holds rows lg*4+r, col lr of each 16x16 fragment
#pragma unroll
  for (int mi = 0; mi < 4; ++mi)
#pragma unroll
    for (int ni = 0; ni < NFR; ++ni) {
      const int col = col0 + wc * WN + ni * 16 + lr;
#pragma unroll
      for (int r = 0; r < 4; ++r) {
        const int row = row0 + wr * 64 + mi * 16 + lg * 4 + r;
        const float v = acc[mi][ni][r];
        const long ci = coff + (long)row * ldc + col;
        if constexpr (EPI == 0)      Cf[ci] = v + bias[col];
        else if constexpr (EPI == 1) Cb[ci] = (__bf16)(v + bias[col]);
        else if constexpr (EPI == 2) Cf[ci] = v + bias[col] + resid[(long)row * ldc + col];
        else if constexpr (EPI == 3) Cb[ci] = (__bf16)v;
        else                         atomicAdd(&Cf[ci], v);
      }
    }
}

// ---------------- fp32 -> bf16 flat convert (n multiple of 1024) -------
__global__ __launch_bounds__(256)
void conv_f32_bf16_k(const float* __restrict__ s, __bf16* __restrict__ d)
{
  const long i = ((long)blockIdx.x * 256 + threadIdx.x) * 4;
  const float4 v = *(const float4*)&s[i];
  union { __bf16 h[4]; short4 sv; } u;
  u.h[0] = (__bf16)v.x; u.h[1] = (__bf16)v.y; u.h[2] = (__bf16)v.z; u.h[3] = (__bf16)v.w;
  *(short4*)&d[i] = u.sv;
}

// ---------------- W [K][N] fp32 -> WT [N][K] bf16 ----------------------
__global__ __launch_bounds__(256)
void transpose_wt_k(const float* __restrict__ W, __bf16* __restrict__ WT, int K, int N)
{
  __shared__ float t[32][33];
  const int n0 = blockIdx.x * 32, k0 = blockIdx.y * 32;
  const int tx = threadIdx.x & 31, ty = threadIdx.x >> 5;
  for (int i = ty; i < 32; i += 8)
    t[i][tx] = W[(size_t)(k0 + i) * N + n0 + tx];
  __syncthreads();
  for (int i = ty; i < 32; i += 8)
    WT[(size_t)(n0 + i) * K + k0 + tx] = (__bf16)t[tx][i];
}

// ---------------- RoPE + layout: qkv fp32 -> Q,K [bh][n][64], Vt [bh][64][n]
__global__ __launch_bounds__(256)
void rope_conv_k(const float* __restrict__ qkv, const float* __restrict__ enc,
                 __bf16* __restrict__ Q, __bf16* __restrict__ Kb, __bf16* __restrict__ Vt)
{
  const long idx = (long)blockIdx.x * 256 + threadIdx.x;  // (bn, h, t)
  const int t = (int)(idx & 31);
  const int h = (int)((idx >> 5) & 7);
  const long bn = idx >> 8;
  const int n = (int)(bn & 2047);
  const int d0 = 2 * t, d1 = d0 + 1;
  const long eb = bn * 64;
  const long e1 = (long)Bb * Nn * 64;
  const float f0a = enc[eb + d0], f0b = enc[eb + d1];
  const float f1a = enc[e1 + eb + d0], f1b = enc[e1 + eb + d1];
  const long base = bn * 1536 + (long)h * 192;
  const long bh = (bn >> 11) * 8 + h;
  const long qo = bh * 131072 + (long)n * 64;
  {
    const float x0 = qkv[base + d0 * 3 + 0], x1 = qkv[base + d1 * 3 + 0];
    union { __bf16 hx[2]; unsigned u; } p;
    p.hx[0] = (__bf16)(x0 * f0a - x1 * f1a);
    p.hx[1] = (__bf16)(x1 * f0b + x0 * f1b);
    *(unsigned*)&Q[qo + d0] = p.u;
  }
  {
    const float x0 = qkv[base + d0 * 3 + 1], x1 = qkv[base + d1 * 3 + 1];
    union { __bf16 hx[2]; unsigned u; } p;
    p.hx[0] = (__bf16)(x0 * f0a - x1 * f1a);
    p.hx[1] = (__bf16)(x1 * f0b + x0 * f1b);
    *(unsigned*)&Kb[qo + d0] = p.u;
  }
  Vt[bh * 131072 + (long)d0 * 2048 + n] = (__bf16)qkv[base + d0 * 3 + 2];
  Vt[bh * 131072 + (long)d1 * 2048 + n] = (__bf16)qkv[base + d1 * 3 + 2];
}

// ---------------- in-place row softmax on bf16 S, scale 1/8 ------------
__global__ __launch_bounds__(256)
void softmax_bf16_k(__bf16* __restrict__ S)
{
  __bf16* row = S + (size_t)blockIdx.x * 2048;
  const int tid = threadIdx.x;
  __shared__ float red[256];
  short8v raw = *(short8v*)&row[tid * 8];
  float v[8];
  float mx = -1e30f;
#pragma unroll
  for (int i = 0; i < 8; ++i) {
    v[i] = (float)__builtin_bit_cast(__bf16, (short)raw[i]) * 0.125f;
    mx = fmaxf(mx, v[i]);
  }
  red[tid] = mx; __syncthreads();
  for (int s = 128; s > 0; s >>= 1) {
    if (tid < s) red[tid] = fmaxf(red[tid], red[tid + s]);
    __syncthreads();
  }
  mx = red[0]; __syncthreads();
  float sm = 0.f;
#pragma unroll
  for (int i = 0; i < 8; ++i) { v[i] = __expf(v[i] - mx); sm += v[i]; }
  red[tid] = sm; __syncthreads();
  for (int s = 128; s > 0; s >>= 1) {
    if (tid < s) red[tid] += red[tid + s];
    __syncthreads();
  }
  const float inv = 1.f / red[0];
  short8v outv;
#pragma unroll
  for (int i = 0; i < 8; ++i)
    outv[i] = __builtin_bit_cast(short, (__bf16)(v[i] * inv));
  *(short8v*)&row[tid * 8] = outv;
}

// ---------------- in-place LayerNorm + exact GELU: h fp32 -> g bf16 ----
__global__ __launch_bounds__(256)
void ln_gelu_k(float* __restrict__ H, const float* __restrict__ g, const float* __restrict__ be)
{
  float* row = H + (size_t)blockIdx.x * 1024;
  __bf16* grow = (__bf16*)row;
  const int tid = threadIdx.x;
  __shared__ float rs_[256], rq_[256];
  const float4 v4 = *(const float4*)&row[tid * 4];
  const float v[4] = {v4.x, v4.y, v4.z, v4.w};
  float s = 0.f, sq = 0.f;
#pragma unroll
  for (int i = 0; i < 4; ++i) { s += v[i]; sq += v[i] * v[i]; }
  rs_[tid] = s; rq_[tid] = sq; __syncthreads();
  for (int st = 128; st > 0; st >>= 1) {
    if (tid < st) { rs_[tid] += rs_[tid + st]; rq_[tid] += rq_[tid + st]; }
    __syncthreads();
  }
  const float mu = rs_[0] * (1.f / 1024.f);
  const float var = rq_[0] * (1.f / 1024.f) - mu * mu;
  const float rstd = rsqrtf(var + 1e-5f);
  union { __bf16 h[4]; short4 sv; } u;
#pragma unroll
  for (int i = 0; i < 4; ++i) {
    const int c = tid * 4 + i;
    const float y = (v[i] - mu) * rstd * g[c] + be[c];
    u.h[i] = (__bf16)(0.5f * y * (1.f + erff(y * 0.70710678118f)));
  }
  *(short4*)&grow[tid * 4] = u.sv;
}

extern "C" void kernel_launch(void* const* d_in, const int* in_sizes, int n_in,
                              void* d_out, int out_size, void* d_ws, size_t ws_size,
                              hipStream_t stream)
{
  const float* x[2]   = {(const float*)d_in[0], (const float*)d_in[1]};
  const float* enc[2] = {(const float*)d_in[2], (const float*)d_in[3]};
  const float* Wqkv  = (const float*)d_in[4];
  const float* bqkv  = (const float*)d_in[5];
  const float* Wproj = (const float*)d_in[6];
  const float* bproj = (const float*)d_in[7];
  const float* W1    = (const float*)d_in[8];
  const float* b1    = (const float*)d_in[9];
  const float* ln_g  = (const float*)d_in[10];
  const float* ln_b  = (const float*)d_in[11];
  const float* W2    = (const float*)d_in[12];
  const float* b2    = (const float*)d_in[13];

  float* ws = (float*)d_ws;
  // Arena A1 (floats [0, 12,582,912)):
  float*  qkvf = ws;                               // [8192][1536] fp32 (dies at rope)
  __bf16* Sb   = (__bf16*)ws;                      // [32][256][2048] bf16 chunk (attn)
  float*  O    = ws + 8388608;                     // [8192][512] fp32 (attn out)
  float*  hbuf = ws;                               // [8192][1024] fp32 (post-attn)
  __bf16* gbuf = (__bf16*)ws;                      // in-place bf16 over hbuf, pitch 2048
  // Arena A2:
  __bf16* Qb   = (__bf16*)(ws + 12582912);         // [32][2048][64]
  __bf16* Kb   = Qb + 4194304;
  __bf16* Vt   = Kb + 4194304;                     // [32][64][2048]
  __bf16* Ob   = Qb;                               // alias after attention
  __bf16* msgb = Kb;                               // alias after attention
  // A3 / A4:
  __bf16* xb    = (__bf16*)(ws + 18874368);        // [8192][512]
  __bf16* WqkvT = (__bf16*)(ws + 20971520);        // [1536][512]
  __bf16* WprojT= WqkvT + 786432;                  // [512][512]
  __bf16* W1T   = WprojT + 262144;                 // [1024][1024]
  __bf16* W2T   = W1T + 1048576;                   // [512][1024]
  // total ws use: 22,282,240 floats = 89.1 MB

  // weight transpose+convert (once per call)
  transpose_wt_k<<<dim3(48, 16), 256, 0, stream>>>(Wqkv, WqkvT, 512, 1536);
  transpose_wt_k<<<dim3(16, 16), 256, 0, stream>>>(Wproj, WprojT, 512, 512);
  transpose_wt_k<<<dim3(32, 32), 256, 0, stream>>>(W1, W1T, 1024, 1024);
  transpose_wt_k<<<dim3(16, 32), 256, 0, stream>>>(W2, W2T, 1024, 512);

  for (int blk = 0; blk < 2; ++blk) {
    conv_f32_bf16_k<<<4096, 256, 0, stream>>>(x[blk], xb);
    // 1. qkv = x @ Wqkv + bqkv -> fp32 [8192][1536]
    gemm_mfma<4, 0, 0><<<dim3(64, 12, 1), 256, 0, stream>>>(
        xb, nullptr, WqkvT, bqkv, nullptr, qkvf, nullptr,
        512, 512, 1536, 0, 512, 0, 0, 0, 0, 0);
    // 2. RoPE + split into Q,K,Vt bf16
    rope_conv_k<<<8192, 256, 0, stream>>>(qkvf, enc[blk], Qb, Kb, Vt);
    // 3. attention
    hipMemsetAsync(O, 0, (size_t)4194304 * 4, stream);
    for (int c = 0; c < NCHUNK; ++c) {
      const int n0 = c * CHUNK;
      gemm_mfma<4, 0, 3><<<dim3(2, 16, 32), 256, 0, stream>>>(
          Qb + (size_t)n0 * 64, nullptr, Kb, nullptr, nullptr, nullptr, Sb,
          64, 64, 2048, 0, 64, 0, 131072, 131072, 4194304, 524288);
      softmax_bf16_k<<<32 * CHUNK, 256, 0, stream>>>(Sb);
      gemm_mfma<2, 0, 4><<<dim3(2, 1, 256), 256, 0, stream>>>(
          Sb, nullptr, Vt, nullptr, nullptr, O + (size_t)n0 * 512, nullptr,
          2048, 2048, 512, 0, 256, 3, 524288, 131072, 1048576, 64);
    }
    conv_f32_bf16_k<<<4096, 256, 0, stream>>>(O, Ob);
    // 4. message = o @ Wproj + bproj -> bf16 [8192][512]
    gemm_mfma<4, 0, 1><<<dim3(64, 4, 1), 256, 0, stream>>>(
        Ob, nullptr, WprojT, bproj, nullptr, nullptr, msgb,
        512, 512, 512, 0, 512, 0, 0, 0, 0, 0);
    // 5. h = [x | message] @ W1 + b1 -> fp32 [8192][1024]
    gemm_mfma<4, 1, 0><<<dim3(64, 8, 1), 256, 0, stream>>>(
        xb, msgb, W1T, b1, nullptr, hbuf, nullptr,
        512, 1024, 1024, 512, 1024, 0, 0, 0, 0, 0);
    // 6. LayerNorm + GELU in place (fp32 -> bf16, pitch 2048)
    ln_gelu_k<<<8192, 256, 0, stream>>>(hbuf, ln_g, ln_b);
    // 7. out = x + g @ W2 + b2 -> fp32
    gemm_mfma<4, 0, 2><<<dim3(64, 4, 1), 256, 0, stream>>>(
        gbuf, nullptr, W2T, b2, x[blk], (float*)d_out + (size_t)blk * 4194304, nullptr,
        2048, 1024, 512, 0, 1024, 0, 0, 0, 0, 0);
  }
}

// Round 4
// 415.990 us; speedup vs baseline: 14.3775x; 2.7118x over previous
//
#include <hip/hip_runtime.h>
#include <hip/hip_bf16.h>

typedef __attribute__((ext_vector_type(8))) short   short8v;
typedef __attribute__((ext_vector_type(8))) __bf16  bf16x8;
typedef __attribute__((ext_vector_type(4))) float   f32x4;

constexpr int Bb = 4, Nn = 2048;
constexpr int MROWS = 8192;

#define GLOAD_LDS(src, dst) \
  __builtin_amdgcn_global_load_lds((__attribute__((address_space(1))) unsigned int*)(src), \
                                   (__attribute__((address_space(3))) unsigned int*)(dst), 16, 0, 0)

__device__ __forceinline__ unsigned pack_bf16(float lo, float hi) {
  union { __bf16 h[2]; unsigned u; } t;
  t.h[0] = (__bf16)lo; t.h[1] = (__bf16)hi;
  return t.u;
}

// =====================================================================
// MFMA GEMM: C[M,N] = A[M,K] @ B[K,N] (+bias)(+resid), B passed as B^T [N][K].
// Tile 128x128, BK=32, 256 threads = 4 waves (2x2).
// AMODE 0: dense A. AMODE 1: concat (A cols [0,K1) | A2 cols [K1,K)).
// EPI 0: fp32 +bias | 1: bf16 +bias | 2: fp32 +bias+resid
// =====================================================================
template<int AMODE, int EPI>
__global__ __launch_bounds__(256)
void gemm_mfma(const __bf16* __restrict__ A, const __bf16* __restrict__ A2,
               const __bf16* __restrict__ BT,
               const float* __restrict__ bias, const float* __restrict__ resid,
               float* __restrict__ Cf, __bf16* __restrict__ Cb,
               int lda, int ldb, int ldc, int K1, int K)
{
  __shared__ __align__(16) __bf16 As[128 * 32];
  __shared__ __align__(16) __bf16 Bs[128 * 32];
  const int tid = threadIdx.x;
  const int w = tid >> 6, l = tid & 63;
  const int wr = w >> 1, wc = w & 1;
  const int lr = l & 15, lg = l >> 4;
  const int row0 = blockIdx.x * 128, col0 = blockIdx.y * 128;

  f32x4 acc[4][4];
#pragma unroll
  for (int i = 0; i < 4; ++i)
#pragma unroll
    for (int j = 0; j < 4; ++j) acc[i][j] = (f32x4){0.f, 0.f, 0.f, 0.f};

  const int srow = l >> 2;
  const int skk  = (l & 3) * 8;

  for (int k0 = 0; k0 < K; k0 += 32) {
    for (int s = w; s < 8; s += 4) {
      const int m = s * 16 + srow;
      const __bf16* src;
      if constexpr (AMODE == 0) {
        src = A + (size_t)(row0 + m) * lda + k0 + skk;
      } else {
        const int gk = k0 + skk;
        src = (gk < K1) ? A  + (size_t)(row0 + m) * lda + gk
                        : A2 + (size_t)(row0 + m) * lda + (gk - K1);
      }
      GLOAD_LDS(src, &As[s * 512]);
    }
    for (int s = w; s < 8; s += 4) {
      const int n = s * 16 + srow;
      GLOAD_LDS(BT + (size_t)(col0 + n) * ldb + k0 + skk, &Bs[s * 512]);
    }
    __syncthreads();
    bf16x8 af[4], bfv[4];
#pragma unroll
    for (int mi = 0; mi < 4; ++mi)
      af[mi] = *(const bf16x8*)&As[(wr * 64 + mi * 16 + lr) * 32 + lg * 8];
#pragma unroll
    for (int ni = 0; ni < 4; ++ni)
      bfv[ni] = *(const bf16x8*)&Bs[(wc * 64 + ni * 16 + lr) * 32 + lg * 8];
#pragma unroll
    for (int mi = 0; mi < 4; ++mi)
#pragma unroll
      for (int ni = 0; ni < 4; ++ni)
        acc[mi][ni] = __builtin_amdgcn_mfma_f32_16x16x32_bf16(af[mi], bfv[ni], acc[mi][ni], 0, 0, 0);
    __syncthreads();
  }
#pragma unroll
  for (int mi = 0; mi < 4; ++mi)
#pragma unroll
    for (int ni = 0; ni < 4; ++ni) {
      const int col = col0 + wc * 64 + ni * 16 + lr;
#pragma unroll
      for (int r = 0; r < 4; ++r) {
        const int row = row0 + wr * 64 + mi * 16 + lg * 4 + r;
        const float v = acc[mi][ni][r];
        const long ci = (long)row * ldc + col;
        if constexpr (EPI == 0)      Cf[ci] = v + bias[col];
        else if constexpr (EPI == 1) Cb[ci] = (__bf16)(v + bias[col]);
        else                         Cf[ci] = v + bias[col] + resid[(long)row * ldc + col];
      }
    }
}

// =====================================================================
// Flash attention. Grid (16 qtiles, 32 bh), 256 thr = 4 waves x 32 q-rows.
// Q,K: [bh][n][64] bf16. V: [bh][64][n] bf16 (transposed). Out: [bn][h*64+d] bf16.
// Computes S^T = mfma(K, Q) so kv-reduce is a 2-shfl column reduce; P^T feeds
// PV B-operand via cndmask+shfl (no LDS round trip for P).
// =====================================================================
__global__ __launch_bounds__(256, 2)
void fa_k(const __bf16* __restrict__ Qg, const __bf16* __restrict__ Kg,
          const __bf16* __restrict__ Vg, __bf16* __restrict__ Ob)
{
  __shared__ __align__(16) __bf16 Ks[8192];   // [128 kv][64 d], granule-swizzled
  __shared__ __align__(16) __bf16 Vs[8192];   // [64 d][128 kv], granule-swizzled
  const int tid = threadIdx.x;
  const int w = tid >> 6, l = tid & 63;
  const int lr = l & 15, lg = l >> 4;
  const int bh = blockIdx.y;
  const __bf16* Qp = Qg + (size_t)bh * 131072;
  const __bf16* Kp = Kg + (size_t)bh * 131072;
  const __bf16* Vp = Vg + (size_t)bh * 131072;
  const int q0 = blockIdx.x * 128 + w * 32;

  bf16x8 qf[2][2];
#pragma unroll
  for (int nf = 0; nf < 2; ++nf)
#pragma unroll
    for (int kk = 0; kk < 2; ++kk)
      qf[nf][kk] = *(const bf16x8*)&Qp[(size_t)(q0 + nf * 16 + lr) * 64 + kk * 32 + lg * 8];

  f32x4 oacc[4][2];
#pragma unroll
  for (int i = 0; i < 4; ++i)
#pragma unroll
    for (int j = 0; j < 2; ++j) oacc[i][j] = (f32x4){0.f, 0.f, 0.f, 0.f};
  float m_run[2] = {-1e30f, -1e30f}, lsum[2] = {0.f, 0.f};

  const int Sa = (lg & 1) * 32 + lr, Sb2 = Sa + 16;
  const bool hi = (lg >> 1) & 1;

  for (int kv0 = 0; kv0 < 2048; kv0 += 128) {
    // ---- stage K[128][64] and V[64][128] tiles (pre-swizzled source) ----
#pragma unroll
    for (int i = 0; i < 4; ++i) {
      const int s = w + 4 * i;
      { const int g = s * 64 + l, r = g >> 3, c = g & 7;
        GLOAD_LDS(Kp + (size_t)(kv0 + r) * 64 + ((c ^ (r & 7)) * 8), &Ks[s * 512]); }
      { const int g = s * 64 + l, r = g >> 4, c = g & 15;
        GLOAD_LDS(Vp + (size_t)r * 2048 + kv0 + ((c ^ (r & 15)) * 8), &Vs[s * 512]); }
    }
    __syncthreads();

    // ---- S^T[128 kv][32 q] = K @ Q^T ----
    f32x4 sacc[8][2];
#pragma unroll
    for (int i = 0; i < 8; ++i)
#pragma unroll
      for (int j = 0; j < 2; ++j) sacc[i][j] = (f32x4){0.f, 0.f, 0.f, 0.f};
#pragma unroll
    for (int kk = 0; kk < 2; ++kk) {
      bf16x8 ka[8];
#pragma unroll
      for (int mf = 0; mf < 8; ++mf)
        ka[mf] = *(const bf16x8*)&Ks[(mf * 16 + lr) * 64 + (((kk * 4 + lg) ^ (lr & 7)) * 8)];
#pragma unroll
      for (int mf = 0; mf < 8; ++mf)
#pragma unroll
        for (int nf = 0; nf < 2; ++nf)
          sacc[mf][nf] = __builtin_amdgcn_mfma_f32_16x16x32_bf16(ka[mf], qf[nf][kk], sacc[mf][nf], 0, 0, 0);
    }

    // ---- online softmax over kv (rows of S^T); col q = lane's lr ----
    unsigned pk[8][2][2];
#pragma unroll
    for (int nf = 0; nf < 2; ++nf) {
      float tm = -1e30f;
#pragma unroll
      for (int mf = 0; mf < 8; ++mf)
#pragma unroll
        for (int r = 0; r < 4; ++r) {
          sacc[mf][nf][r] *= 0.125f;
          tm = fmaxf(tm, sacc[mf][nf][r]);
        }
      tm = fmaxf(tm, __shfl_xor(tm, 16, 64));
      tm = fmaxf(tm, __shfl_xor(tm, 32, 64));
      const float mn = fmaxf(m_run[nf], tm);
      const float corr = __expf(m_run[nf] - mn);
      m_run[nf] = mn;
      float rs = 0.f;
#pragma unroll
      for (int mf = 0; mf < 8; ++mf) {
        const float p0 = __expf(sacc[mf][nf][0] - mn);
        const float p1 = __expf(sacc[mf][nf][1] - mn);
        const float p2 = __expf(sacc[mf][nf][2] - mn);
        const float p3 = __expf(sacc[mf][nf][3] - mn);
        rs += (p0 + p1) + (p2 + p3);
        pk[mf][nf][0] = pack_bf16(p0, p1);
        pk[mf][nf][1] = pack_bf16(p2, p3);
      }
      rs += __shfl_xor(rs, 16, 64);
      rs += __shfl_xor(rs, 32, 64);
      lsum[nf] = lsum[nf] * corr + rs;
#pragma unroll
      for (int mo = 0; mo < 4; ++mo)
#pragma unroll
        for (int r = 0; r < 4; ++r) oacc[mo][nf][r] *= corr;
    }

    // ---- O^T[64 d][32 q] += V^T @ P^T ----
#pragma unroll
    for (int kf = 0; kf < 4; ++kf) {
      bf16x8 va[4];
#pragma unroll
      for (int mo = 0; mo < 4; ++mo)
        va[mo] = *(const bf16x8*)&Vs[(mo * 16 + lr) * 128 + ((((kf * 4 + lg) ^ lr) & 15) * 8)];
      bf16x8 bfr[2];
#pragma unroll
      for (int nf = 0; nf < 2; ++nf) {
        const unsigned s0 = hi ? pk[kf * 2 + 1][nf][0] : pk[kf * 2][nf][0];
        const unsigned s1 = hi ? pk[kf * 2 + 1][nf][1] : pk[kf * 2][nf][1];
        union { unsigned u[4]; bf16x8 v; } ub;
        ub.u[0] = (unsigned)__shfl((int)s0, Sa, 64);
        ub.u[1] = (unsigned)__shfl((int)s1, Sa, 64);
        ub.u[2] = (unsigned)__shfl((int)s0, Sb2, 64);
        ub.u[3] = (unsigned)__shfl((int)s1, Sb2, 64);
        bfr[nf] = ub.v;
      }
#pragma unroll
      for (int mo = 0; mo < 4; ++mo)
#pragma unroll
        for (int nf = 0; nf < 2; ++nf)
          oacc[mo][nf] = __builtin_amdgcn_mfma_f32_16x16x32_bf16(va[mo], bfr[nf], oacc[mo][nf], 0, 0, 0);
    }
    __syncthreads();
  }

  // ---- epilogue: O^T frag (row d = mo*16+lg*4+r, col q = nf*16+lr) ----
  const int b = bh >> 3, h = bh & 7;
#pragma unroll
  for (int nf = 0; nf < 2; ++nf) {
    const float inv = 1.f / lsum[nf];
    const long row = (long)b * 2048 + q0 + nf * 16 + lr;
#pragma unroll
    for (int mo = 0; mo < 4; ++mo) {
      union { __bf16 h4[4]; short4 s4; } u;
#pragma unroll
      for (int r = 0; r < 4; ++r) u.h4[r] = (__bf16)(oacc[mo][nf][r] * inv);
      *(short4*)&Ob[row * 512 + h * 64 + mo * 16 + lg * 4] = u.s4;
    }
  }
}

// ---------------- fp32 -> bf16 flat convert ----------------------------
__global__ __launch_bounds__(256)
void conv_f32_bf16_k(const float* __restrict__ s, __bf16* __restrict__ d)
{
  const long i = ((long)blockIdx.x * 256 + threadIdx.x) * 4;
  const float4 v = *(const float4*)&s[i];
  union { __bf16 h[4]; short4 sv; } u;
  u.h[0] = (__bf16)v.x; u.h[1] = (__bf16)v.y; u.h[2] = (__bf16)v.z; u.h[3] = (__bf16)v.w;
  *(short4*)&d[i] = u.sv;
}

// ---------------- W [K][N] fp32 -> WT [N][K] bf16 (PERM: qkv col shuffle)
template<int PERM>
__global__ __launch_bounds__(256)
void transpose_wt_k(const float* __restrict__ W, __bf16* __restrict__ WT, int K, int N)
{
  __shared__ float t[32][33];
  const int n0 = blockIdx.x * 32, k0 = blockIdx.y * 32;
  const int tx = threadIdx.x & 31, ty = threadIdx.x >> 5;
  for (int i = ty; i < 32; i += 8)
    t[i][tx] = W[(size_t)(k0 + i) * N + n0 + tx];
  __syncthreads();
  for (int i = ty; i < 32; i += 8) {
    int drow = n0 + i;
    if constexpr (PERM) {
      const int h = drow / 192, rem = drow % 192;
      drow = (rem % 3) * 512 + h * 64 + rem / 3;
    }
    WT[(size_t)drow * K + k0 + tx] = (__bf16)t[tx][i];
  }
}

// ---------------- permute qkv bias ------------------------------------
__global__ void bperm_k(const float* __restrict__ b, float* __restrict__ bp)
{
  const int i = blockIdx.x * 256 + threadIdx.x;
  if (i < 1536) {
    const int h = i / 192, rem = i % 192;
    bp[(rem % 3) * 512 + h * 64 + rem / 3] = b[i];
  }
}

// ---------------- RoPE: de-interleaved qkvf -> Qb,Kb [bh][n][64] bf16 --
__global__ __launch_bounds__(256)
void rope2_k(const float* __restrict__ qkvf, const float* __restrict__ enc,
             __bf16* __restrict__ Qb, __bf16* __restrict__ Kb)
{
  const long idx = (long)blockIdx.x * 256 + threadIdx.x;  // (bn, h, t)
  const int t = (int)(idx & 31);
  const int h = (int)((idx >> 5) & 7);
  const long bn = idx >> 8;
  const int n = (int)(bn & 2047);
  const int d0 = 2 * t;
  const long eb = bn * 64;
  const long e1 = (long)Bb * Nn * 64;
  const float f0a = enc[eb + d0], f0b = enc[eb + d0 + 1];
  const float f1a = enc[e1 + eb + d0], f1b = enc[e1 + eb + d0 + 1];
  const long rbase = bn * 1536 + (long)h * 64 + d0;
  const long qo = ((bn >> 11) * 8 + h) * 131072 + (long)n * 64 + d0;
  {
    const float2 v = *(const float2*)&qkvf[rbase];
    union { __bf16 hx[2]; unsigned u; } p;
    p.hx[0] = (__bf16)(v.x * f0a - v.y * f1a);
    p.hx[1] = (__bf16)(v.y * f0b + v.x * f1b);
    *(unsigned*)&Qb[qo] = p.u;
  }
  {
    const float2 v = *(const float2*)&qkvf[rbase + 512];
    union { __bf16 hx[2]; unsigned u; } p;
    p.hx[0] = (__bf16)(v.x * f0a - v.y * f1a);
    p.hx[1] = (__bf16)(v.y * f0b + v.x * f1b);
    *(unsigned*)&Kb[qo] = p.u;
  }
}

// ---------------- V section -> Vt [bh][64][2048] bf16 (LDS transpose) --
__global__ __launch_bounds__(256)
void vt_k(const float* __restrict__ qkvf, __bf16* __restrict__ Vt)
{
  __shared__ float t[64][65];
  const int bh = blockIdx.x, ntile = blockIdx.y;
  const int b = bh >> 3, h = bh & 7;
  const int tx = threadIdx.x & 63, ty = threadIdx.x >> 6;
  const int n0 = ntile * 64;
  for (int i = ty; i < 64; i += 4)
    t[i][tx] = qkvf[((size_t)b * 2048 + n0 + i) * 1536 + 1024 + h * 64 + tx];
  __syncthreads();
  for (int j = ty; j < 64; j += 4)
    Vt[(size_t)bh * 131072 + (size_t)j * 2048 + n0 + tx] = (__bf16)t[tx][j];
}

// ---------------- in-place LayerNorm + exact GELU: h fp32 -> g bf16 ----
__global__ __launch_bounds__(256)
void ln_gelu_k(float* __restrict__ H, const float* __restrict__ g, const float* __restrict__ be)
{
  float* row = H + (size_t)blockIdx.x * 1024;
  __bf16* grow = (__bf16*)row;
  const int tid = threadIdx.x;
  __shared__ float rs_[256], rq_[256];
  const float4 v4 = *(const float4*)&row[tid * 4];
  const float v[4] = {v4.x, v4.y, v4.z, v4.w};
  float s = 0.f, sq = 0.f;
#pragma unroll
  for (int i = 0; i < 4; ++i) { s += v[i]; sq += v[i] * v[i]; }
  rs_[tid] = s; rq_[tid] = sq; __syncthreads();
  for (int st = 128; st > 0; st >>= 1) {
    if (tid < st) { rs_[tid] += rs_[tid + st]; rq_[tid] += rq_[tid + st]; }
    __syncthreads();
  }
  const float mu = rs_[0] * (1.f / 1024.f);
  const float var = rq_[0] * (1.f / 1024.f) - mu * mu;
  const float rstd = rsqrtf(var + 1e-5f);
  union { __bf16 h[4]; short4 sv; } u;
#pragma unroll
  for (int i = 0; i < 4; ++i) {
    const int c = tid * 4 + i;
    const float y = (v[i] - mu) * rstd * g[c] + be[c];
    u.h[i] = (__bf16)(0.5f * y * (1.f + erff(y * 0.70710678118f)));
  }
  *(short4*)&grow[tid * 4] = u.sv;
}

extern "C" void kernel_launch(void* const* d_in, const int* in_sizes, int n_in,
                              void* d_out, int out_size, void* d_ws, size_t ws_size,
                              hipStream_t stream)
{
  const float* x[2]   = {(const float*)d_in[0], (const float*)d_in[1]};
  const float* enc[2] = {(const float*)d_in[2], (const float*)d_in[3]};
  const float* Wqkv  = (const float*)d_in[4];
  const float* bqkv  = (const float*)d_in[5];
  const float* Wproj = (const float*)d_in[6];
  const float* bproj = (const float*)d_in[7];
  const float* W1    = (const float*)d_in[8];
  const float* b1    = (const float*)d_in[9];
  const float* ln_g  = (const float*)d_in[10];
  const float* ln_b  = (const float*)d_in[11];
  const float* W2    = (const float*)d_in[12];
  const float* b2    = (const float*)d_in[13];

  float* ws = (float*)d_ws;
  // Arena A1 [0, 12582912) floats — sequential lifetimes:
  float*  qkvf = ws;                      // [8192][1536] fp32 (dead after rope2+vt)
  __bf16* Ob   = (__bf16*)ws;             // [8192][512] bf16 (fa output)
  __bf16* msgb = (__bf16*)(ws + 2097152); // [8192][512] bf16
  float*  hbuf = ws + 4194304;            // [8192][1024] fp32
  __bf16* gbuf = (__bf16*)hbuf;           // in-place bf16, pitch 2048
  // Arena A2:
  __bf16* Qb = (__bf16*)(ws + 12582912);  // [32][2048][64]
  __bf16* Kb = Qb + 4194304;
  __bf16* Vt = Kb + 4194304;              // [32][64][2048]
  // A3:
  __bf16* xb    = (__bf16*)(ws + 18874368);
  __bf16* WqkvT = (__bf16*)(ws + 20971520);   // permuted rows [1536][512]
  __bf16* WprojT= WqkvT + 786432;
  __bf16* W1T   = WprojT + 262144;
  __bf16* W2T   = W1T + 1048576;
  float*  bqkvp = ws + 22282240;              // permuted qkv bias (1536)
  // total: 22,283,776 floats = 89.1 MB

  transpose_wt_k<1><<<dim3(48, 16), 256, 0, stream>>>(Wqkv, WqkvT, 512, 1536);
  transpose_wt_k<0><<<dim3(16, 16), 256, 0, stream>>>(Wproj, WprojT, 512, 512);
  transpose_wt_k<0><<<dim3(32, 32), 256, 0, stream>>>(W1, W1T, 1024, 1024);
  transpose_wt_k<0><<<dim3(16, 32), 256, 0, stream>>>(W2, W2T, 1024, 512);
  bperm_k<<<6, 256, 0, stream>>>(bqkv, bqkvp);

  for (int blk = 0; blk < 2; ++blk) {
    conv_f32_bf16_k<<<4096, 256, 0, stream>>>(x[blk], xb);
    // 1. qkv = x @ Wqkv(permuted) + bqkv -> fp32 [Q|K|V] sections
    gemm_mfma<0, 0><<<dim3(64, 12), 256, 0, stream>>>(
        xb, nullptr, WqkvT, bqkvp, nullptr, qkvf, nullptr, 512, 512, 1536, 0, 512);
    // 2. RoPE -> Qb,Kb ; V -> Vt
    rope2_k<<<8192, 256, 0, stream>>>(qkvf, enc[blk], Qb, Kb);
    vt_k<<<dim3(32, 32), 256, 0, stream>>>(qkvf, Vt);
    // 3. flash attention -> Ob [bn][h*64+d] bf16
    fa_k<<<dim3(16, 32), 256, 0, stream>>>(Qb, Kb, Vt, Ob);
    // 4. message = o @ Wproj + bproj -> bf16
    gemm_mfma<0, 1><<<dim3(64, 4), 256, 0, stream>>>(
        Ob, nullptr, WprojT, bproj, nullptr, nullptr, msgb, 512, 512, 512, 0, 512);
    // 5. h = [x | message] @ W1 + b1 -> fp32
    gemm_mfma<1, 0><<<dim3(64, 8), 256, 0, stream>>>(
        xb, msgb, W1T, b1, nullptr, hbuf, nullptr, 512, 1024, 1024, 512, 1024);
    // 6. LayerNorm + GELU in place (fp32 -> bf16, pitch 2048)
    ln_gelu_k<<<8192, 256, 0, stream>>>(hbuf, ln_g, ln_b);
    // 7. out = x + g @ W2 + b2 -> fp32
    gemm_mfma<0, 2><<<dim3(64, 4), 256, 0, stream>>>(
        gbuf, nullptr, W2T, b2, x[blk], (float*)d_out + (size_t)blk * 4194304, nullptr,
        2048, 1024, 512, 0, 1024);
  }
}